// Round 11
// baseline (163.115 us; speedup 1.0000x reference)
//
#include <hip/hip_runtime.h>

typedef unsigned short u16;
typedef unsigned int   u32;
typedef short bf16x8 __attribute__((ext_vector_type(8)));
typedef float f32x4  __attribute__((ext_vector_type(4)));

__device__ __forceinline__ u16 f2bf(float f) {
  union { float f; u32 u; } v; v.f = f;
  u32 u = v.u;
  u += 0x7fffu + ((u >> 16) & 1u);   // RNE
  return (u16)(u >> 16);
}

__device__ __forceinline__ void splitbf(float x, u16& hi, u16& lo) {
  hi = f2bf(x);
  union { u32 u; float f; } r; r.u = (u32)hi << 16;
  lo = f2bf(x - r.f);
}

__device__ __forceinline__ float bflo(u32 p) {
  union { u32 u; float f; } v; v.u = p << 16; return v.f;
}
__device__ __forceinline__ float bfhi(u32 p) {
  union { u32 u; float f; } v; v.u = p & 0xffff0000u; return v.f;
}
__device__ __forceinline__ u32 cvtpk(float lo, float hi) {
  u32 r;
  asm("v_cvt_pk_bf16_f32 %0, %1, %2" : "=v"(r) : "v"(lo), "v"(hi));
  return r;
}
__device__ __forceinline__ void gload_lds16(const void* src, void* dst) {
  __builtin_amdgcn_global_load_lds(
      (const __attribute__((address_space(1))) u32*)src,
      (__attribute__((address_space(3))) u32*)dst, 16, 0, 0);
}

// ---------------------------------------------------------------------------
// k_prepT: LDS-tile transpose of the big layer-1 weights + small layouts.
// ---------------------------------------------------------------------------
__global__ __launch_bounds__(256) void k_prepT(
    const float* __restrict__ mW1, const float* __restrict__ pW1,
    const float* __restrict__ aW1, const float* __restrict__ aW2,
    const float* __restrict__ mW2, const float* __restrict__ pW2,
    const float* __restrict__ pb1, const float* __restrict__ pb2,
    const float* __restrict__ pW3,
    u16* __restrict__ Wcath, u16* __restrict__ Wcatl,
    u16* __restrict__ aW1Th, u16* __restrict__ aW1Tl,
    u16* __restrict__ Wckg,
    float* __restrict__ aW2p, float* __restrict__ mW2p,
    u16* __restrict__ W2kg, float* __restrict__ pb1p,
    float* __restrict__ pb2p, float* __restrict__ w3p) {
  __shared__ float ls[64][153];
  const int tid = threadIdx.x;
  const int task = blockIdx.y;
  const int e0 = blockIdx.x * 64;
  if (task == 5) {
    const int stride = 36 * 256;
    const int t0 = blockIdx.x * 256 + tid;
    for (int t = t0; t < 152*160; t += stride) {
      int k = t / 160, h = t % 160;
      bool ok = (k < 150 && h < 150);
      aW2p[t] = ok ? aW2[k*150 + h] : 0.f;
      mW2p[t] = ok ? mW2[k*150 + h] : 0.f;
    }
    for (int t = t0; t < 24*1280; t += stride) {
      int kg = t / 1280, rem = t % 1280;
      int s = rem / 160, n = rem % 160;
      int k = kg*8 + s;
      float v = (k < 150 && n < 150) ? pW2[k*150 + n] : 0.f;
      W2kg[(size_t)kg*1280 + n*8 + s] = f2bf(v);
    }
    for (int t = t0; t < 160; t += stride) {
      pb1p[t] = (t < 150) ? pb1[t] : 0.f;
      pb2p[t] = (t < 150) ? pb2[t] : 0.f;
      w3p[t]  = (t < 150) ? pW3[t] : 0.f;
    }
    return;
  }
  if (task == 3 && e0 >= 768) return;
  const float* src;
  if (task == 0)      src = mW1;
  else if (task == 1) src = pW1;
  else if (task == 2) src = pW1 + (size_t)2304 * 150;
  else if (task == 3) src = aW1;
  else                src = pW1 + (size_t)4608 * 150;
  for (int t = tid; t < 9600; t += 256) {
    int r = t / 150, c = t - r * 150;
    ls[r][c] = src[(size_t)(e0 + r) * 150 + c];
  }
  __syncthreads();
  if (task < 3) {
    u16* dh = Wcath + (size_t)task * 160 * 2304;
    u16* dl = Wcatl + (size_t)task * 160 * 2304;
    for (int t = tid; t < 10240; t += 256) {
      int n = t >> 6, r = t & 63;
      float v = (n < 150) ? ls[r][n] : 0.f;
      u16 h, l; splitbf(v, h, l);
      dh[(size_t)n * 2304 + e0 + r] = h;
      dl[(size_t)n * 2304 + e0 + r] = l;
    }
  } else if (task == 3) {
    for (int t = tid; t < 10240; t += 256) {
      int n = t >> 6, r = t & 63;
      float v = (n < 150) ? ls[r][n] : 0.f;
      u16 h, l; splitbf(v, h, l);
      aW1Th[(size_t)n * 768 + e0 + r] = h;
      aW1Tl[(size_t)n * 768 + e0 + r] = l;
    }
  } else {
    for (int t = tid; t < 10240; t += 256) {
      int n = t >> 6, r = t & 63;
      int e = e0 + r;
      float v = (n < 150) ? ls[r][n] : 0.f;
      Wckg[((size_t)(e >> 3) * 160 + n) * 8 + (e & 7)] = f2bf(v);
    }
  }
}

// ---------------------------------------------------------------------------
// attn layer1 (split-bf16 MFMA GEMM, split-K x4): raw partials
// ---------------------------------------------------------------------------
__global__ __launch_bounds__(256) void k_attn1(
    const float* __restrict__ e, const u16* __restrict__ Wh,
    const u16* __restrict__ Wl, float* __restrict__ h1p) {
  __shared__ u16 lXh[32*64], lXl[32*64], lWh[160*64], lWl[160*64];
  const int tid = threadIdx.x, lane = tid & 63, w = tid >> 6;
  const int wm = w & 1, wh = w >> 1;
  const int m0 = blockIdx.x * 32;
  const int z  = blockIdx.y;
  f32x4 acc[5] = {};
  for (int e0 = z*192; e0 < (z+1)*192; e0 += 64) {
    {
      int r = tid >> 3, ec = tid & 7;
      const float* src = e + (size_t)(m0 + r)*768 + e0 + ec*8;
      float4 x0 = *(const float4*)src, x1 = *(const float4*)(src + 4);
      float xs[8] = {x0.x,x0.y,x0.z,x0.w,x1.x,x1.y,x1.z,x1.w};
      u16 hb[8], lb[8];
#pragma unroll
      for (int q = 0; q < 8; ++q) splitbf(xs[q], hb[q], lb[q]);
      int off = (r*128 + ec*16) ^ ((r & 7) << 4);
      *(uint4*)((char*)lXh + off) = make_uint4(
        (u32)hb[0]|((u32)hb[1]<<16), (u32)hb[2]|((u32)hb[3]<<16),
        (u32)hb[4]|((u32)hb[5]<<16), (u32)hb[6]|((u32)hb[7]<<16));
      *(uint4*)((char*)lXl + off) = make_uint4(
        (u32)lb[0]|((u32)lb[1]<<16), (u32)lb[2]|((u32)lb[3]<<16),
        (u32)lb[4]|((u32)lb[5]<<16), (u32)lb[6]|((u32)lb[7]<<16));
    }
#pragma unroll
    for (int t = 0; t < 5; ++t) {
      int c = tid + t*256;
      int h = c >> 3, ec = c & 7;
      int off = (h*128 + ec*16) ^ ((h & 7) << 4);
      *(uint4*)((char*)lWh + off) = *(const uint4*)(Wh + (size_t)h*768 + e0 + ec*8);
      *(uint4*)((char*)lWl + off) = *(const uint4*)(Wl + (size_t)h*768 + e0 + ec*8);
    }
    __syncthreads();
#pragma unroll
    for (int ks = 0; ks < 2; ++ks) {
      int eb = ks*64 + ((lane >> 4) << 4);
      int ar = wm*16 + (lane & 15);
      bf16x8 Ah = *(const bf16x8*)((const char*)lXh + ((ar*128 + eb) ^ ((ar & 7) << 4)));
      bf16x8 Al = *(const bf16x8*)((const char*)lXl + ((ar*128 + eb) ^ ((ar & 7) << 4)));
#pragma unroll
      for (int t = 0; t < 5; ++t) {
        int br = wh*80 + t*16 + (lane & 15);
        bf16x8 Bh = *(const bf16x8*)((const char*)lWh + ((br*128 + eb) ^ ((br & 7) << 4)));
        bf16x8 Bl = *(const bf16x8*)((const char*)lWl + ((br*128 + eb) ^ ((br & 7) << 4)));
        acc[t] = __builtin_amdgcn_mfma_f32_16x16x32_bf16(Ah, Bh, acc[t], 0, 0, 0);
        acc[t] = __builtin_amdgcn_mfma_f32_16x16x32_bf16(Al, Bh, acc[t], 0, 0, 0);
        acc[t] = __builtin_amdgcn_mfma_f32_16x16x32_bf16(Ah, Bl, acc[t], 0, 0, 0);
      }
    }
    __syncthreads();
  }
#pragma unroll
  for (int t = 0; t < 5; ++t) {
    int n = wh*80 + t*16 + (lane & 15);
#pragma unroll
    for (int r = 0; r < 4; ++r) {
      int m = m0 + wm*16 + ((lane >> 4) << 2) + r;
      h1p[((size_t)z*2048 + m)*160 + n] = acc[t][r];
    }
  }
}

// ---------------------------------------------------------------------------
// attn layers 2+3 (sums 4 split-K partials, bias+relu, then MLP tail)
// ---------------------------------------------------------------------------
__global__ __launch_bounds__(256) void k_attn2(
    const float* __restrict__ h1p, const float* __restrict__ W2p,
    const float* __restrict__ b1, const float* __restrict__ b2,
    const float* __restrict__ w3, const float* __restrict__ b3,
    float* __restrict__ attn) {
  __shared__ float hs[8][160];
  const int tid = threadIdx.x;
  const int t0 = blockIdx.x * 8;
  for (int idx = tid; idx < 1280; idx += 256) {
    int m = idx / 160, h = idx - m * 160;
    float s = 0.f;
#pragma unroll
    for (int z = 0; z < 4; ++z)
      s += h1p[((size_t)z*2048 + t0 + m)*160 + h];
    hs[m][h] = (h < 150) ? fmaxf(s + b1[h], 0.f) : 0.f;
  }
  __syncthreads();
  const int sp = tid >> 5, hb = tid & 31;
  float a2[5] = {0.f,0.f,0.f,0.f,0.f};
  for (int k = 0; k < 150; ++k) {
    float x = hs[sp][k];
#pragma unroll
    for (int q = 0; q < 5; ++q) a2[q] = fmaf(x, W2p[k*160 + hb + 32*q], a2[q]);
  }
  float p = 0.f;
#pragma unroll
  for (int q = 0; q < 5; ++q) {
    int h = hb + 32*q;
    if (h < 150) p += fmaxf(a2[q] + b2[h], 0.f) * w3[h];
  }
  p += __shfl_xor(p, 16, 32);
  p += __shfl_xor(p, 8, 32);
  p += __shfl_xor(p, 4, 32);
  p += __shfl_xor(p, 2, 32);
  p += __shfl_xor(p, 1, 32);
  if (hb == 0) attn[t0 + sp] = p + b3[0];
}

// ---------------------------------------------------------------------------
// g[s] = [e[start], e[end], span_sum]; also writes gkg (k-grouped bf16)
// ---------------------------------------------------------------------------
__global__ __launch_bounds__(256) void k_spans(
    const float* __restrict__ e, const float* __restrict__ attn,
    const int* __restrict__ sstart, const int* __restrict__ swidth,
    float* __restrict__ g, u16* __restrict__ gkg) {
  const int s = blockIdx.x;
  int st = sstart[s];
  int en = st + swidth[s];
  if (en > 2047) en = 2047;
  if (en < 0) en = 0;
  const int tid = threadIdx.x;
  for (int d = tid; d < 768; d += 256) {
    float v0 = e[(size_t)st*768 + d];
    float v1 = e[(size_t)en*768 + d];
    float acc = 0.f;
    for (int t = st; t <= en; ++t) acc += e[(size_t)t*768 + d] * attn[t];
    g[s*2304 + d]        = v0;
    g[s*2304 + 768 + d]  = v1;
    g[s*2304 + 1536 + d] = acc;
    int c0 = d, c1 = 768 + d, c2 = 1536 + d;
    gkg[((size_t)(c0>>3)*256 + s)*8 + (c0&7)] = f2bf(v0);
    gkg[((size_t)(c1>>3)*256 + s)*8 + (c1&7)] = f2bf(v1);
    gkg[((size_t)(c2>>3)*256 + s)*8 + (c2&7)] = f2bf(acc);
  }
}

// ---------------------------------------------------------------------------
// span layer1 (split-bf16 MFMA GEMM, split-K x6): raw partials
// ---------------------------------------------------------------------------
__global__ __launch_bounds__(128) void k_span1(
    const float* __restrict__ g, const u16* __restrict__ Wh,
    const u16* __restrict__ Wl, float* __restrict__ pp) {
  __shared__ u16 lXh[16*64], lXl[16*64], lWh[160*64], lWl[160*64];
  const int tid = threadIdx.x, lane = tid & 63;
  const int wh = tid >> 6;
  const int m0 = blockIdx.x * 16;
  const int n0 = blockIdx.y * 160;
  const int z  = blockIdx.z;
  f32x4 acc[5] = {};
  for (int e0 = z*384; e0 < (z+1)*384; e0 += 64) {
    {
      int r = tid >> 3, ec = tid & 7;
      const float* src = g + (size_t)(m0 + r)*2304 + e0 + ec*8;
      float4 x0 = *(const float4*)src, x1 = *(const float4*)(src + 4);
      float xs[8] = {x0.x,x0.y,x0.z,x0.w,x1.x,x1.y,x1.z,x1.w};
      u16 hb[8], lb[8];
#pragma unroll
      for (int q = 0; q < 8; ++q) splitbf(xs[q], hb[q], lb[q]);
      int off = (r*128 + ec*16) ^ ((r & 7) << 4);
      *(uint4*)((char*)lXh + off) = make_uint4(
        (u32)hb[0]|((u32)hb[1]<<16), (u32)hb[2]|((u32)hb[3]<<16),
        (u32)hb[4]|((u32)hb[5]<<16), (u32)hb[6]|((u32)hb[7]<<16));
      *(uint4*)((char*)lXl + off) = make_uint4(
        (u32)lb[0]|((u32)lb[1]<<16), (u32)lb[2]|((u32)lb[3]<<16),
        (u32)lb[4]|((u32)lb[5]<<16), (u32)lb[6]|((u32)lb[7]<<16));
    }
#pragma unroll
    for (int t = 0; t < 10; ++t) {
      int c = tid + t*128;
      int h = c >> 3, ec = c & 7;
      int off = (h*128 + ec*16) ^ ((h & 7) << 4);
      *(uint4*)((char*)lWh + off) = *(const uint4*)(Wh + (size_t)(n0 + h)*2304 + e0 + ec*8);
      *(uint4*)((char*)lWl + off) = *(const uint4*)(Wl + (size_t)(n0 + h)*2304 + e0 + ec*8);
    }
    __syncthreads();
#pragma unroll
    for (int ks = 0; ks < 2; ++ks) {
      int eb = ks*64 + ((lane >> 4) << 4);
      int ar = lane & 15;
      bf16x8 Ah = *(const bf16x8*)((const char*)lXh + ((ar*128 + eb) ^ ((ar & 7) << 4)));
      bf16x8 Al = *(const bf16x8*)((const char*)lXl + ((ar*128 + eb) ^ ((ar & 7) << 4)));
#pragma unroll
      for (int t = 0; t < 5; ++t) {
        int br = wh*80 + t*16 + (lane & 15);
        bf16x8 Bh = *(const bf16x8*)((const char*)lWh + ((br*128 + eb) ^ ((br & 7) << 4)));
        bf16x8 Bl = *(const bf16x8*)((const char*)lWl + ((br*128 + eb) ^ ((br & 7) << 4)));
        acc[t] = __builtin_amdgcn_mfma_f32_16x16x32_bf16(Ah, Bh, acc[t], 0, 0, 0);
        acc[t] = __builtin_amdgcn_mfma_f32_16x16x32_bf16(Al, Bh, acc[t], 0, 0, 0);
        acc[t] = __builtin_amdgcn_mfma_f32_16x16x32_bf16(Ah, Bl, acc[t], 0, 0, 0);
      }
    }
    __syncthreads();
  }
#pragma unroll
  for (int t = 0; t < 5; ++t) {
    int nc = n0 + wh*80 + t*16 + (lane & 15);
#pragma unroll
    for (int r = 0; r < 4; ++r) {
      int m = m0 + ((lane >> 4) << 2) + r;
      pp[((size_t)z*256 + m)*480 + nc] = acc[t][r];
    }
  }
}

// ---------------------------------------------------------------------------
// span reduce + layers 2+3 (merged)
// ---------------------------------------------------------------------------
__global__ __launch_bounds__(256) void k_span2r(
    const float* __restrict__ pp, const float* __restrict__ mb1,
    const float* __restrict__ W2p, const float* __restrict__ b2,
    const float* __restrict__ w3, const float* __restrict__ b3,
    float* __restrict__ hi, float* __restrict__ hj, float* __restrict__ mo) {
  __shared__ float hs[8][160];
  const int tid = threadIdx.x;
  const int s0 = blockIdx.x * 8;
  for (int idx = tid; idx < 3840; idx += 256) {
    int mr = idx / 480, n = idx - mr * 480;
    int m = s0 + mr;
    float s = 0.f;
#pragma unroll
    for (int z = 0; z < 6; ++z) s += pp[((size_t)z*256 + m)*480 + n];
    if (n < 160)      hs[mr][n] = (n < 150) ? fmaxf(s + mb1[n], 0.f) : 0.f;
    else if (n < 320) hi[m*160 + n - 160] = s;
    else              hj[m*160 + n - 320] = s;
  }
  __syncthreads();
  const int sp = tid >> 5, hb = tid & 31;
  float a2[5] = {0.f,0.f,0.f,0.f,0.f};
  for (int k = 0; k < 150; ++k) {
    float x = hs[sp][k];
#pragma unroll
    for (int q = 0; q < 5; ++q) a2[q] = fmaf(x, W2p[k*160 + hb + 32*q], a2[q]);
  }
  float p = 0.f;
#pragma unroll
  for (int q = 0; q < 5; ++q) {
    int h = hb + 32*q;
    if (h < 150) p += fmaxf(a2[q] + b2[h], 0.f) * w3[h];
  }
  p += __shfl_xor(p, 16, 32);
  p += __shfl_xor(p, 8, 32);
  p += __shfl_xor(p, 4, 32);
  p += __shfl_xor(p, 2, 32);
  p += __shfl_xor(p, 1, 32);
  if (hb == 0) mo[s0 + sp] = p + b3[0];
}

// ---------------------------------------------------------------------------
// k_hij9: fused big einsum + pairwise MLP, SCALE-ON-A version.
// ONE block per i (256 blocks, 512 threads = 8 waves as wj(4) x wh(2);
// wave tile 64j x 80h, j-span 256).
//   hij[j,h] = sum_k (gbf[j,k]*g[i,k]) * Wc[k,h]
// A = gkg global->VGPR (dbuf'd in regs, loads issued BEFORE MFMA so latency
//     hides under the full MFMA phase); the i-scale is applied to A in regs
//     (VALU pipe, overlaps matrix pipe).
// B = RAW Wckg staged via pure global_load_lds DMA, double-buffered; no cvt,
//     no ds_write, no lgkm-coupled staging tail.
// End-of-chunk: s_waitcnt vmcnt(12) lgkmcnt(0) + raw s_barrier — the 12
// newer reg-loads stay in flight; all older DMAs are drained (T4 counted).
// LDS: B dbuf 2x20480 @0; then h1' [20kg][256j][8] @0 (80K);
//      B2 @81920 (20K); red @102400. Total 104448.
// ---------------------------------------------------------------------------
__global__ __launch_bounds__(512, 2) void k_hij9(
    const float* __restrict__ g, const u16* __restrict__ gkg,
    const u16* __restrict__ Wckg, const float* __restrict__ hi,
    const float* __restrict__ hj, const float* __restrict__ pb1p,
    const u16* __restrict__ W2kg, const float* __restrict__ pb2p,
    const float* __restrict__ w3p, const float* __restrict__ pb3,
    const float* __restrict__ mv, float* __restrict__ out) {
  __shared__ __align__(16) char smem[104448];
  const int tid = threadIdx.x, lane = tid & 63, w = tid >> 6;
  const int wj = w & 3, wh = w >> 2;
  const int i = blockIdx.x;
  const float* grow = g + (size_t)i * 2304;

  f32x4 acc[4][5] = {};
  bf16x8 afC[8], afN[8];     // raw A granules (cur / next)
  float4 gsC[4], gsN[4];     // scale vectors: [ks*2+0]=k0..3, [ks*2+1]=k4..7

  // A granule base: lane holds j=(wj*64+q*16+(lane&15)), kg=(lane>>4)
  const u16* pA = gkg + (((lane >> 4) * 256) + wj * 64 + (lane & 15)) * 8;
  const float* pG = grow + (lane >> 4) * 8;
  const int bB = (((lane >> 4) * 160) + wh * 80 + (lane & 15)) * 16;

  auto issueB = [&](int buf, int t) {
    const u16* src = Wckg + (size_t)t * 10240 + lane * 8;
    char* dst = smem + buf * 20480;
    gload_lds16(src + (w * 2 + 0) * 512, dst + (w * 2 + 0) * 1024);
    gload_lds16(src + (w * 2 + 1) * 512, dst + (w * 2 + 1) * 1024);
    if (w < 4) gload_lds16(src + (16 + w) * 512, dst + (16 + w) * 1024);
  };
  auto loadA = [&](int t, bf16x8* af, float4* gs) {
    const u16* p = pA + (size_t)t * 16384;
#pragma unroll
    for (int ks = 0; ks < 2; ++ks) {
#pragma unroll
      for (int q = 0; q < 4; ++q)
        af[ks * 4 + q] = *(const bf16x8*)(p + ks * 8192 + q * 128);
      const float* gp = pG + t * 64 + ks * 32;
      gs[ks * 2 + 0] = *(const float4*)gp;
      gs[ks * 2 + 1] = *(const float4*)(gp + 4);
    }
  };

  // prologue: DMAs first (oldest), then 12 reg loads
  issueB(0, 0);
  __builtin_amdgcn_sched_barrier(0);
  loadA(0, afC, gsC);
  __builtin_amdgcn_sched_barrier(0);
  asm volatile("s_waitcnt vmcnt(12)" ::: "memory");
  __builtin_amdgcn_s_barrier();
  __builtin_amdgcn_sched_barrier(0);

  for (int t = 0; t < 36; ++t) {
    const int buf = t & 1;
    if (t < 35) {
      issueB(buf ^ 1, t + 1);
      __builtin_amdgcn_sched_barrier(0);
      loadA(t + 1, afN, gsN);
    }
    __builtin_amdgcn_sched_barrier(0);
    const char* Bb = smem + buf * 20480;
    __builtin_amdgcn_s_setprio(1);
#pragma unroll
    for (int ks = 0; ks < 2; ++ks) {
      const float4 ga = gsC[ks * 2], gb = gsC[ks * 2 + 1];
      bf16x8 as[4];
#pragma unroll
      for (int q = 0; q < 4; ++q) {
        union { bf16x8 b; uint4 u; } v, r;
        v.b = afC[ks * 4 + q];
        r.u.x = cvtpk(bflo(v.u.x) * ga.x, bfhi(v.u.x) * ga.y);
        r.u.y = cvtpk(bflo(v.u.y) * ga.z, bfhi(v.u.y) * ga.w);
        r.u.z = cvtpk(bflo(v.u.z) * gb.x, bfhi(v.u.z) * gb.y);
        r.u.w = cvtpk(bflo(v.u.w) * gb.z, bfhi(v.u.w) * gb.w);
        as[q] = r.b;
      }
#pragma unroll
      for (int u = 0; u < 5; ++u) {
        bf16x8 bfr = *(const bf16x8*)(Bb + bB + ks * 10240 + u * 256);
#pragma unroll
        for (int q = 0; q < 4; ++q)
          acc[q][u] = __builtin_amdgcn_mfma_f32_16x16x32_bf16(
              as[q], bfr, acc[q][u], 0, 0, 0);
      }
    }
    __builtin_amdgcn_s_setprio(0);
    if (t < 35) {
#pragma unroll
      for (int k = 0; k < 8; ++k) afC[k] = afN[k];
#pragma unroll
      for (int k = 0; k < 4; ++k) gsC[k] = gsN[k];
    }
    __builtin_amdgcn_sched_barrier(0);
    // DMAs (older than the 12 reg loads) drained; ds_reads drained; the
    // 12 A/g reg loads for t+1 legally stay in flight across the barrier.
    asm volatile("s_waitcnt vmcnt(12) lgkmcnt(0)" ::: "memory");
    __builtin_amdgcn_s_barrier();
    __builtin_amdgcn_sched_barrier(0);
  }

  // ---- epilogue1: h1 = relu(hij + hi + hj + pb1) -> LDS bf16 [20][256][8] --
  {
    float hib[5];
#pragma unroll
    for (int u = 0; u < 5; ++u) {
      int h = wh * 80 + u * 16 + (lane & 15);
      hib[u] = hi[i * 160 + h] + pb1p[h];
    }
#pragma unroll
    for (int q = 0; q < 4; ++q) {
      int jl = wj * 64 + q * 16 + ((lane >> 4) << 2);
#pragma unroll
      for (int r = 0; r < 4; ++r) {
        const float* hjr = hj + (size_t)(jl + r) * 160;
#pragma unroll
        for (int u = 0; u < 5; ++u) {
          int h = wh * 80 + u * 16 + (lane & 15);
          float v = fmaxf(acc[q][u][r] + hib[u] + hjr[h], 0.f);
          *(u16*)(smem + ((h >> 3) * 256 + jl + r) * 16 + (h & 7) * 2) = f2bf(v);
        }
      }
    }
  }
  __syncthreads();

  // ---- GEMM2: h2 = h1' @ W2 (K=160), 3 chunks (8,8,4 kgrps) ----
  f32x4 acc2[4][5] = {};
  for (int c = 0; c < 3; ++c) {
    const int G64 = (c < 2) ? 20 : 10;
    for (int g0 = w; g0 < G64; g0 += 8) {
      const u16* src = W2kg + ((size_t)c * 1280 + g0 * 64 + lane) * 8;
      gload_lds16(src, smem + 81920 + g0 * 1024);
    }
    __syncthreads();
    const int nks = (c < 2) ? 2 : 1;
    for (int ks = 0; ks < nks; ++ks) {
      const int kl = ks * 4 + (lane >> 4);
      bf16x8 af2[4];
#pragma unroll
      for (int q = 0; q < 4; ++q)
        af2[q] = *(const bf16x8*)(smem + ((c * 8 + kl) * 256 + wj * 64 + q * 16 + (lane & 15)) * 16);
#pragma unroll
      for (int u = 0; u < 5; ++u) {
        bf16x8 b2 = *(const bf16x8*)(smem + 81920 + (kl * 160 + wh * 80 + u * 16 + (lane & 15)) * 16);
#pragma unroll
        for (int q = 0; q < 4; ++q)
          acc2[q][u] = __builtin_amdgcn_mfma_f32_16x16x32_bf16(af2[q], b2, acc2[q][u], 0, 0, 0);
      }
    }
    __syncthreads();
  }

  // ---- epilogue2: s = relu(h2 + pb2).w3 ; out = clip((mi+mj+s)/3) ----
  {
    float w3v[5], b2v[5];
#pragma unroll
    for (int u = 0; u < 5; ++u) {
      int h2 = wh * 80 + u * 16 + (lane & 15);
      w3v[u] = w3p[h2]; b2v[u] = pb2p[h2];
    }
#pragma unroll
    for (int q = 0; q < 4; ++q) {
#pragma unroll
      for (int r = 0; r < 4; ++r) {
        float sp = 0.f;
#pragma unroll
        for (int u = 0; u < 5; ++u)
          sp += fmaxf(acc2[q][u][r] + b2v[u], 0.f) * w3v[u];
        sp += __shfl_xor(sp, 1);
        sp += __shfl_xor(sp, 2);
        sp += __shfl_xor(sp, 4);
        sp += __shfl_xor(sp, 8);
        if ((lane & 15) == 0) {
          int jl = wj * 64 + q * 16 + ((lane >> 4) << 2) + r;
          *(float*)(smem + 102400 + (jl * 2 + wh) * 4) = sp;
        }
      }
    }
  }
  __syncthreads();
  if (tid < 256) {
    float s = *(const float*)(smem + 102400 + tid * 8) +
              *(const float*)(smem + 102400 + tid * 8 + 4) + pb3[0];
    float v = (mv[i] + mv[tid] + s) * (1.f / 3.f);
    out[i * 256 + tid] = fminf(fmaxf(v, 0.f), 1.f);
  }
}

// ---------------------------------------------------------------------------
extern "C" void kernel_launch(void* const* d_in, const int* in_sizes, int n_in,
                              void* d_out, int out_size, void* d_ws, size_t ws_size,
                              hipStream_t stream) {
  (void)in_sizes; (void)n_in; (void)out_size; (void)ws_size;
  const float* e    = (const float*)d_in[0];
  const int*   sst  = (const int*)d_in[1];
  const int*   swd  = (const int*)d_in[2];
  const float* aW1  = (const float*)d_in[3];
  const float* ab1  = (const float*)d_in[4];
  const float* aW2  = (const float*)d_in[5];
  const float* ab2  = (const float*)d_in[6];
  const float* aW3  = (const float*)d_in[7];
  const float* ab3  = (const float*)d_in[8];
  const float* mW1  = (const float*)d_in[9];
  const float* mb1  = (const float*)d_in[10];
  const float* mW2  = (const float*)d_in[11];
  const float* mb2  = (const float*)d_in[12];
  const float* mW3  = (const float*)d_in[13];
  const float* mb3  = (const float*)d_in[14];
  const float* pW1  = (const float*)d_in[15];
  const float* pb1  = (const float*)d_in[16];
  const float* pW2  = (const float*)d_in[17];
  const float* pb2  = (const float*)d_in[18];
  const float* pW3  = (const float*)d_in[19];
  const float* pb3  = (const float*)d_in[20];
  float* out = (float*)d_out;

  char* ws = (char*)d_ws;
  size_t off = 0;
  auto alloc = [&](size_t bytes) -> char* {
    char* p = ws + off;
    off += (bytes + 255) & ~(size_t)255;
    return p;
  };
  float* attn  = (float*)alloc(2048ULL*4);
  float* g     = (float*)alloc(256ULL*2304*4);
  float* hi    = (float*)alloc(256ULL*160*4);
  float* hj    = (float*)alloc(256ULL*160*4);
  float* mv    = (float*)alloc(256ULL*4);
  float* h1p   = (float*)alloc(4ULL*2048*160*4);
  float* pp    = (float*)alloc(6ULL*256*480*4);
  u16*   aW1Th = (u16*)alloc(160ULL*768*2);
  u16*   aW1Tl = (u16*)alloc(160ULL*768*2);
  u16*   Wcath = (u16*)alloc(480ULL*2304*2);
  u16*   Wcatl = (u16*)alloc(480ULL*2304*2);
  float* aW2p  = (float*)alloc(152ULL*160*4);
  float* mW2p  = (float*)alloc(152ULL*160*4);
  u16*   gkg   = (u16*)alloc(288ULL*256*8*2);
  u16*   Wckg  = (u16*)alloc(288ULL*160*8*2);
  u16*   W2kg  = (u16*)alloc(24ULL*1280*2);
  float* pb1p  = (float*)alloc(160ULL*4);
  float* pb2p  = (float*)alloc(160ULL*4);
  float* w3p   = (float*)alloc(160ULL*4);

  k_prepT<<<dim3(36, 6), 256, 0, stream>>>(mW1, pW1, aW1, aW2, mW2, pW2,
                                           pb1, pb2, pW3,
                                           Wcath, Wcatl, aW1Th, aW1Tl, Wckg,
                                           aW2p, mW2p, W2kg, pb1p, pb2p, w3p);
  k_attn1<<<dim3(64, 4), 256, 0, stream>>>(e, aW1Th, aW1Tl, h1p);
  k_attn2<<<256, 256, 0, stream>>>(h1p, aW2p, ab1, ab2, aW3, ab3, attn);
  k_spans<<<256, 256, 0, stream>>>(e, attn, sst, swd, g, gkg);
  k_span1<<<dim3(16, 3, 6), 128, 0, stream>>>(g, Wcath, Wcatl, pp);
  k_span2r<<<32, 256, 0, stream>>>(pp, mb1, mW2p, mb2, mW3, mb3, hi, hj, mv);
  k_hij9<<<256, 512, 0, stream>>>(g, gkg, Wckg, hi, hj, pb1p,
                                  W2kg, pb2p, w3p, pb3, mv, out);
}

// Round 12
// 162.444 us; speedup vs baseline: 1.0041x; 1.0041x over previous
//
#include <hip/hip_runtime.h>

typedef unsigned short u16;
typedef unsigned int   u32;
typedef short bf16x8 __attribute__((ext_vector_type(8)));
typedef float f32x4  __attribute__((ext_vector_type(4)));

__device__ __forceinline__ u16 f2bf(float f) {
  union { float f; u32 u; } v; v.f = f;
  u32 u = v.u;
  u += 0x7fffu + ((u >> 16) & 1u);   // RNE
  return (u16)(u >> 16);
}

__device__ __forceinline__ void splitbf(float x, u16& hi, u16& lo) {
  hi = f2bf(x);
  union { u32 u; float f; } r; r.u = (u32)hi << 16;
  lo = f2bf(x - r.f);
}

__device__ __forceinline__ float bflo(u32 p) {
  union { u32 u; float f; } v; v.u = p << 16; return v.f;
}
__device__ __forceinline__ float bfhi(u32 p) {
  union { u32 u; float f; } v; v.u = p & 0xffff0000u; return v.f;
}
__device__ __forceinline__ u32 cvtpk(float lo, float hi) {
  u32 r;
  asm("v_cvt_pk_bf16_f32 %0, %1, %2" : "=v"(r) : "v"(lo), "v"(hi));
  return r;
}
__device__ __forceinline__ void gload_lds16(const void* src, void* dst) {
  __builtin_amdgcn_global_load_lds(
      (const __attribute__((address_space(1))) u32*)src,
      (__attribute__((address_space(3))) u32*)dst, 16, 0, 0);
}

// ---------------------------------------------------------------------------
// k_prepT: LDS-tile transpose of the big layer-1 weights + small layouts.
// ---------------------------------------------------------------------------
__global__ __launch_bounds__(256) void k_prepT(
    const float* __restrict__ mW1, const float* __restrict__ pW1,
    const float* __restrict__ aW1, const float* __restrict__ aW2,
    const float* __restrict__ mW2, const float* __restrict__ pW2,
    const float* __restrict__ pb1, const float* __restrict__ pb2,
    const float* __restrict__ pW3,
    u16* __restrict__ Wcath, u16* __restrict__ Wcatl,
    u16* __restrict__ aW1Th, u16* __restrict__ aW1Tl,
    u16* __restrict__ Wckg,
    float* __restrict__ aW2p, float* __restrict__ mW2p,
    u16* __restrict__ W2kg, float* __restrict__ pb1p,
    float* __restrict__ pb2p, float* __restrict__ w3p) {
  __shared__ float ls[64][153];
  const int tid = threadIdx.x;
  const int task = blockIdx.y;
  const int e0 = blockIdx.x * 64;
  if (task == 5) {
    const int stride = 36 * 256;
    const int t0 = blockIdx.x * 256 + tid;
    for (int t = t0; t < 152*160; t += stride) {
      int k = t / 160, h = t % 160;
      bool ok = (k < 150 && h < 150);
      aW2p[t] = ok ? aW2[k*150 + h] : 0.f;
      mW2p[t] = ok ? mW2[k*150 + h] : 0.f;
    }
    for (int t = t0; t < 24*1280; t += stride) {
      int kg = t / 1280, rem = t % 1280;
      int s = rem / 160, n = rem % 160;
      int k = kg*8 + s;
      float v = (k < 150 && n < 150) ? pW2[k*150 + n] : 0.f;
      W2kg[(size_t)kg*1280 + n*8 + s] = f2bf(v);
    }
    for (int t = t0; t < 160; t += stride) {
      pb1p[t] = (t < 150) ? pb1[t] : 0.f;
      pb2p[t] = (t < 150) ? pb2[t] : 0.f;
      w3p[t]  = (t < 150) ? pW3[t] : 0.f;
    }
    return;
  }
  if (task == 3 && e0 >= 768) return;
  const float* src;
  if (task == 0)      src = mW1;
  else if (task == 1) src = pW1;
  else if (task == 2) src = pW1 + (size_t)2304 * 150;
  else if (task == 3) src = aW1;
  else                src = pW1 + (size_t)4608 * 150;
  for (int t = tid; t < 9600; t += 256) {
    int r = t / 150, c = t - r * 150;
    ls[r][c] = src[(size_t)(e0 + r) * 150 + c];
  }
  __syncthreads();
  if (task < 3) {
    u16* dh = Wcath + (size_t)task * 160 * 2304;
    u16* dl = Wcatl + (size_t)task * 160 * 2304;
    for (int t = tid; t < 10240; t += 256) {
      int n = t >> 6, r = t & 63;
      float v = (n < 150) ? ls[r][n] : 0.f;
      u16 h, l; splitbf(v, h, l);
      dh[(size_t)n * 2304 + e0 + r] = h;
      dl[(size_t)n * 2304 + e0 + r] = l;
    }
  } else if (task == 3) {
    for (int t = tid; t < 10240; t += 256) {
      int n = t >> 6, r = t & 63;
      float v = (n < 150) ? ls[r][n] : 0.f;
      u16 h, l; splitbf(v, h, l);
      aW1Th[(size_t)n * 768 + e0 + r] = h;
      aW1Tl[(size_t)n * 768 + e0 + r] = l;
    }
  } else {
    for (int t = tid; t < 10240; t += 256) {
      int n = t >> 6, r = t & 63;
      int e = e0 + r;
      float v = (n < 150) ? ls[r][n] : 0.f;
      Wckg[((size_t)(e >> 3) * 160 + n) * 8 + (e & 7)] = f2bf(v);
    }
  }
}

// ---------------------------------------------------------------------------
// attn layer1 (split-bf16 MFMA GEMM, split-K x4): raw partials
// ---------------------------------------------------------------------------
__global__ __launch_bounds__(256) void k_attn1(
    const float* __restrict__ e, const u16* __restrict__ Wh,
    const u16* __restrict__ Wl, float* __restrict__ h1p) {
  __shared__ u16 lXh[32*64], lXl[32*64], lWh[160*64], lWl[160*64];
  const int tid = threadIdx.x, lane = tid & 63, w = tid >> 6;
  const int wm = w & 1, wh = w >> 1;
  const int m0 = blockIdx.x * 32;
  const int z  = blockIdx.y;
  f32x4 acc[5] = {};
  for (int e0 = z*192; e0 < (z+1)*192; e0 += 64) {
    {
      int r = tid >> 3, ec = tid & 7;
      const float* src = e + (size_t)(m0 + r)*768 + e0 + ec*8;
      float4 x0 = *(const float4*)src, x1 = *(const float4*)(src + 4);
      float xs[8] = {x0.x,x0.y,x0.z,x0.w,x1.x,x1.y,x1.z,x1.w};
      u16 hb[8], lb[8];
#pragma unroll
      for (int q = 0; q < 8; ++q) splitbf(xs[q], hb[q], lb[q]);
      int off = (r*128 + ec*16) ^ ((r & 7) << 4);
      *(uint4*)((char*)lXh + off) = make_uint4(
        (u32)hb[0]|((u32)hb[1]<<16), (u32)hb[2]|((u32)hb[3]<<16),
        (u32)hb[4]|((u32)hb[5]<<16), (u32)hb[6]|((u32)hb[7]<<16));
      *(uint4*)((char*)lXl + off) = make_uint4(
        (u32)lb[0]|((u32)lb[1]<<16), (u32)lb[2]|((u32)lb[3]<<16),
        (u32)lb[4]|((u32)lb[5]<<16), (u32)lb[6]|((u32)lb[7]<<16));
    }
#pragma unroll
    for (int t = 0; t < 5; ++t) {
      int c = tid + t*256;
      int h = c >> 3, ec = c & 7;
      int off = (h*128 + ec*16) ^ ((h & 7) << 4);
      *(uint4*)((char*)lWh + off) = *(const uint4*)(Wh + (size_t)h*768 + e0 + ec*8);
      *(uint4*)((char*)lWl + off) = *(const uint4*)(Wl + (size_t)h*768 + e0 + ec*8);
    }
    __syncthreads();
#pragma unroll
    for (int ks = 0; ks < 2; ++ks) {
      int eb = ks*64 + ((lane >> 4) << 4);
      int ar = wm*16 + (lane & 15);
      bf16x8 Ah = *(const bf16x8*)((const char*)lXh + ((ar*128 + eb) ^ ((ar & 7) << 4)));
      bf16x8 Al = *(const bf16x8*)((const char*)lXl + ((ar*128 + eb) ^ ((ar & 7) << 4)));
#pragma unroll
      for (int t = 0; t < 5; ++t) {
        int br = wh*80 + t*16 + (lane & 15);
        bf16x8 Bh = *(const bf16x8*)((const char*)lWh + ((br*128 + eb) ^ ((br & 7) << 4)));
        bf16x8 Bl = *(const bf16x8*)((const char*)lWl + ((br*128 + eb) ^ ((br & 7) << 4)));
        acc[t] = __builtin_amdgcn_mfma_f32_16x16x32_bf16(Ah, Bh, acc[t], 0, 0, 0);
        acc[t] = __builtin_amdgcn_mfma_f32_16x16x32_bf16(Al, Bh, acc[t], 0, 0, 0);
        acc[t] = __builtin_amdgcn_mfma_f32_16x16x32_bf16(Ah, Bl, acc[t], 0, 0, 0);
      }
    }
    __syncthreads();
  }
#pragma unroll
  for (int t = 0; t < 5; ++t) {
    int n = wh*80 + t*16 + (lane & 15);
#pragma unroll
    for (int r = 0; r < 4; ++r) {
      int m = m0 + wm*16 + ((lane >> 4) << 2) + r;
      h1p[((size_t)z*2048 + m)*160 + n] = acc[t][r];
    }
  }
}

// ---------------------------------------------------------------------------
// attn layers 2+3 (sums 4 split-K partials, bias+relu, then MLP tail)
// ---------------------------------------------------------------------------
__global__ __launch_bounds__(256) void k_attn2(
    const float* __restrict__ h1p, const float* __restrict__ W2p,
    const float* __restrict__ b1, const float* __restrict__ b2,
    const float* __restrict__ w3, const float* __restrict__ b3,
    float* __restrict__ attn) {
  __shared__ float hs[8][160];
  const int tid = threadIdx.x;
  const int t0 = blockIdx.x * 8;
  for (int idx = tid; idx < 1280; idx += 256) {
    int m = idx / 160, h = idx - m * 160;
    float s = 0.f;
#pragma unroll
    for (int z = 0; z < 4; ++z)
      s += h1p[((size_t)z*2048 + t0 + m)*160 + h];
    hs[m][h] = (h < 150) ? fmaxf(s + b1[h], 0.f) : 0.f;
  }
  __syncthreads();
  const int sp = tid >> 5, hb = tid & 31;
  float a2[5] = {0.f,0.f,0.f,0.f,0.f};
  for (int k = 0; k < 150; ++k) {
    float x = hs[sp][k];
#pragma unroll
    for (int q = 0; q < 5; ++q) a2[q] = fmaf(x, W2p[k*160 + hb + 32*q], a2[q]);
  }
  float p = 0.f;
#pragma unroll
  for (int q = 0; q < 5; ++q) {
    int h = hb + 32*q;
    if (h < 150) p += fmaxf(a2[q] + b2[h], 0.f) * w3[h];
  }
  p += __shfl_xor(p, 16, 32);
  p += __shfl_xor(p, 8, 32);
  p += __shfl_xor(p, 4, 32);
  p += __shfl_xor(p, 2, 32);
  p += __shfl_xor(p, 1, 32);
  if (hb == 0) attn[t0 + sp] = p + b3[0];
}

// ---------------------------------------------------------------------------
// g[s] = [e[start], e[end], span_sum]; also writes gkg (k-grouped bf16)
// ---------------------------------------------------------------------------
__global__ __launch_bounds__(256) void k_spans(
    const float* __restrict__ e, const float* __restrict__ attn,
    const int* __restrict__ sstart, const int* __restrict__ swidth,
    float* __restrict__ g, u16* __restrict__ gkg) {
  const int s = blockIdx.x;
  int st = sstart[s];
  int en = st + swidth[s];
  if (en > 2047) en = 2047;
  if (en < 0) en = 0;
  const int tid = threadIdx.x;
  for (int d = tid; d < 768; d += 256) {
    float v0 = e[(size_t)st*768 + d];
    float v1 = e[(size_t)en*768 + d];
    float acc = 0.f;
    for (int t = st; t <= en; ++t) acc += e[(size_t)t*768 + d] * attn[t];
    g[s*2304 + d]        = v0;
    g[s*2304 + 768 + d]  = v1;
    g[s*2304 + 1536 + d] = acc;
    int c0 = d, c1 = 768 + d, c2 = 1536 + d;
    gkg[((size_t)(c0>>3)*256 + s)*8 + (c0&7)] = f2bf(v0);
    gkg[((size_t)(c1>>3)*256 + s)*8 + (c1&7)] = f2bf(v1);
    gkg[((size_t)(c2>>3)*256 + s)*8 + (c2&7)] = f2bf(acc);
  }
}

// ---------------------------------------------------------------------------
// span layer1 (split-bf16 MFMA GEMM, split-K x6): raw partials
// ---------------------------------------------------------------------------
__global__ __launch_bounds__(128) void k_span1(
    const float* __restrict__ g, const u16* __restrict__ Wh,
    const u16* __restrict__ Wl, float* __restrict__ pp) {
  __shared__ u16 lXh[16*64], lXl[16*64], lWh[160*64], lWl[160*64];
  const int tid = threadIdx.x, lane = tid & 63;
  const int wh = tid >> 6;
  const int m0 = blockIdx.x * 16;
  const int n0 = blockIdx.y * 160;
  const int z  = blockIdx.z;
  f32x4 acc[5] = {};
  for (int e0 = z*384; e0 < (z+1)*384; e0 += 64) {
    {
      int r = tid >> 3, ec = tid & 7;
      const float* src = g + (size_t)(m0 + r)*2304 + e0 + ec*8;
      float4 x0 = *(const float4*)src, x1 = *(const float4*)(src + 4);
      float xs[8] = {x0.x,x0.y,x0.z,x0.w,x1.x,x1.y,x1.z,x1.w};
      u16 hb[8], lb[8];
#pragma unroll
      for (int q = 0; q < 8; ++q) splitbf(xs[q], hb[q], lb[q]);
      int off = (r*128 + ec*16) ^ ((r & 7) << 4);
      *(uint4*)((char*)lXh + off) = make_uint4(
        (u32)hb[0]|((u32)hb[1]<<16), (u32)hb[2]|((u32)hb[3]<<16),
        (u32)hb[4]|((u32)hb[5]<<16), (u32)hb[6]|((u32)hb[7]<<16));
      *(uint4*)((char*)lXl + off) = make_uint4(
        (u32)lb[0]|((u32)lb[1]<<16), (u32)lb[2]|((u32)lb[3]<<16),
        (u32)lb[4]|((u32)lb[5]<<16), (u32)lb[6]|((u32)lb[7]<<16));
    }
#pragma unroll
    for (int t = 0; t < 10; ++t) {
      int c = tid + t*128;
      int h = c >> 3, ec = c & 7;
      int off = (h*128 + ec*16) ^ ((h & 7) << 4);
      *(uint4*)((char*)lWh + off) = *(const uint4*)(Wh + (size_t)(n0 + h)*2304 + e0 + ec*8);
      *(uint4*)((char*)lWl + off) = *(const uint4*)(Wl + (size_t)(n0 + h)*2304 + e0 + ec*8);
    }
    __syncthreads();
#pragma unroll
    for (int ks = 0; ks < 2; ++ks) {
      int eb = ks*64 + ((lane >> 4) << 4);
      int ar = lane & 15;
      bf16x8 Ah = *(const bf16x8*)((const char*)lXh + ((ar*128 + eb) ^ ((ar & 7) << 4)));
      bf16x8 Al = *(const bf16x8*)((const char*)lXl + ((ar*128 + eb) ^ ((ar & 7) << 4)));
#pragma unroll
      for (int t = 0; t < 5; ++t) {
        int br = wh*80 + t*16 + (lane & 15);
        bf16x8 Bh = *(const bf16x8*)((const char*)lWh + ((br*128 + eb) ^ ((br & 7) << 4)));
        bf16x8 Bl = *(const bf16x8*)((const char*)lWl + ((br*128 + eb) ^ ((br & 7) << 4)));
        acc[t] = __builtin_amdgcn_mfma_f32_16x16x32_bf16(Ah, Bh, acc[t], 0, 0, 0);
        acc[t] = __builtin_amdgcn_mfma_f32_16x16x32_bf16(Al, Bh, acc[t], 0, 0, 0);
        acc[t] = __builtin_amdgcn_mfma_f32_16x16x32_bf16(Ah, Bl, acc[t], 0, 0, 0);
      }
    }
    __syncthreads();
  }
#pragma unroll
  for (int t = 0; t < 5; ++t) {
    int nc = n0 + wh*80 + t*16 + (lane & 15);
#pragma unroll
    for (int r = 0; r < 4; ++r) {
      int m = m0 + ((lane >> 4) << 2) + r;
      pp[((size_t)z*256 + m)*480 + nc] = acc[t][r];
    }
  }
}

// ---------------------------------------------------------------------------
// span reduce + layers 2+3 (merged)
// ---------------------------------------------------------------------------
__global__ __launch_bounds__(256) void k_span2r(
    const float* __restrict__ pp, const float* __restrict__ mb1,
    const float* __restrict__ W2p, const float* __restrict__ b2,
    const float* __restrict__ w3, const float* __restrict__ b3,
    float* __restrict__ hi, float* __restrict__ hj, float* __restrict__ mo) {
  __shared__ float hs[8][160];
  const int tid = threadIdx.x;
  const int s0 = blockIdx.x * 8;
  for (int idx = tid; idx < 3840; idx += 256) {
    int mr = idx / 480, n = idx - mr * 480;
    int m = s0 + mr;
    float s = 0.f;
#pragma unroll
    for (int z = 0; z < 6; ++z) s += pp[((size_t)z*256 + m)*480 + n];
    if (n < 160)      hs[mr][n] = (n < 150) ? fmaxf(s + mb1[n], 0.f) : 0.f;
    else if (n < 320) hi[m*160 + n - 160] = s;
    else              hj[m*160 + n - 320] = s;
  }
  __syncthreads();
  const int sp = tid >> 5, hb = tid & 31;
  float a2[5] = {0.f,0.f,0.f,0.f,0.f};
  for (int k = 0; k < 150; ++k) {
    float x = hs[sp][k];
#pragma unroll
    for (int q = 0; q < 5; ++q) a2[q] = fmaf(x, W2p[k*160 + hb + 32*q], a2[q]);
  }
  float p = 0.f;
#pragma unroll
  for (int q = 0; q < 5; ++q) {
    int h = hb + 32*q;
    if (h < 150) p += fmaxf(a2[q] + b2[h], 0.f) * w3[h];
  }
  p += __shfl_xor(p, 16, 32);
  p += __shfl_xor(p, 8, 32);
  p += __shfl_xor(p, 4, 32);
  p += __shfl_xor(p, 2, 32);
  p += __shfl_xor(p, 1, 32);
  if (hb == 0) mo[s0 + sp] = p + b3[0];
}

// ---------------------------------------------------------------------------
// k_hij9: fused big einsum + pairwise MLP, SCALE-ON-A version.
// ONE block per i (256 blocks, 512 threads = 8 waves as wj(4) x wh(2);
// wave tile 64j x 80h, j-span 256).
//   hij[j,h] = sum_k (gbf[j,k]*g[i,k]) * Wc[k,h]
// A = gkg global->VGPR (dbuf'd in regs, loads issued BEFORE MFMA so latency
//     hides under the full MFMA phase); the i-scale is applied to A in regs
//     (VALU pipe, overlaps matrix pipe).
// B = RAW Wckg staged via pure global_load_lds DMA, double-buffered; no cvt,
//     no ds_write, no lgkm-coupled staging tail.
// End-of-chunk: s_waitcnt vmcnt(12) lgkmcnt(0) + raw s_barrier — the 12
// newer reg-loads stay in flight; all older DMAs are drained (T4 counted).
// LDS: B dbuf 2x20480 @0; then h1' [20kg][256j][8] @0 (80K);
//      B2 @81920 (20K); red @102400. Total 104448.
// ---------------------------------------------------------------------------
__global__ __launch_bounds__(512, 2) void k_hij9(
    const float* __restrict__ g, const u16* __restrict__ gkg,
    const u16* __restrict__ Wckg, const float* __restrict__ hi,
    const float* __restrict__ hj, const float* __restrict__ pb1p,
    const u16* __restrict__ W2kg, const float* __restrict__ pb2p,
    const float* __restrict__ w3p, const float* __restrict__ pb3,
    const float* __restrict__ mv, float* __restrict__ out) {
  __shared__ __align__(16) char smem[104448];
  const int tid = threadIdx.x, lane = tid & 63, w = tid >> 6;
  const int wj = w & 3, wh = w >> 2;
  const int i = blockIdx.x;
  const float* grow = g + (size_t)i * 2304;

  f32x4 acc[4][5] = {};
  bf16x8 afC[8], afN[8];     // raw A granules (cur / next)
  float4 gsC[4], gsN[4];     // scale vectors: [ks*2+0]=k0..3, [ks*2+1]=k4..7

  // A granule base: lane holds j=(wj*64+q*16+(lane&15)), kg=(lane>>4)
  const u16* pA = gkg + (((lane >> 4) * 256) + wj * 64 + (lane & 15)) * 8;
  const float* pG = grow + (lane >> 4) * 8;
  const int bB = (((lane >> 4) * 160) + wh * 80 + (lane & 15)) * 16;

  auto issueB = [&](int buf, int t) {
    const u16* src = Wckg + (size_t)t * 10240 + lane * 8;
    char* dst = smem + buf * 20480;
    gload_lds16(src + (w * 2 + 0) * 512, dst + (w * 2 + 0) * 1024);
    gload_lds16(src + (w * 2 + 1) * 512, dst + (w * 2 + 1) * 1024);
    if (w < 4) gload_lds16(src + (16 + w) * 512, dst + (16 + w) * 1024);
  };
  auto loadA = [&](int t, bf16x8* af, float4* gs) {
    const u16* p = pA + (size_t)t * 16384;
#pragma unroll
    for (int ks = 0; ks < 2; ++ks) {
#pragma unroll
      for (int q = 0; q < 4; ++q)
        af[ks * 4 + q] = *(const bf16x8*)(p + ks * 8192 + q * 128);
      const float* gp = pG + t * 64 + ks * 32;
      gs[ks * 2 + 0] = *(const float4*)gp;
      gs[ks * 2 + 1] = *(const float4*)(gp + 4);
    }
  };

  // prologue: DMAs first (oldest), then 12 reg loads
  issueB(0, 0);
  __builtin_amdgcn_sched_barrier(0);
  loadA(0, afC, gsC);
  __builtin_amdgcn_sched_barrier(0);
  asm volatile("s_waitcnt vmcnt(12)" ::: "memory");
  __builtin_amdgcn_s_barrier();
  __builtin_amdgcn_sched_barrier(0);

  for (int t = 0; t < 36; ++t) {
    const int buf = t & 1;
    if (t < 35) {
      issueB(buf ^ 1, t + 1);
      __builtin_amdgcn_sched_barrier(0);
      loadA(t + 1, afN, gsN);
    }
    __builtin_amdgcn_sched_barrier(0);
    const char* Bb = smem + buf * 20480;
    __builtin_amdgcn_s_setprio(1);
#pragma unroll
    for (int ks = 0; ks < 2; ++ks) {
      const float4 ga = gsC[ks * 2], gb = gsC[ks * 2 + 1];
      bf16x8 as[4];
#pragma unroll
      for (int q = 0; q < 4; ++q) {
        union { bf16x8 b; uint4 u; } v, r;
        v.b = afC[ks * 4 + q];
        r.u.x = cvtpk(bflo(v.u.x) * ga.x, bfhi(v.u.x) * ga.y);
        r.u.y = cvtpk(bflo(v.u.y) * ga.z, bfhi(v.u.y) * ga.w);
        r.u.z = cvtpk(bflo(v.u.z) * gb.x, bfhi(v.u.z) * gb.y);
        r.u.w = cvtpk(bflo(v.u.w) * gb.z, bfhi(v.u.w) * gb.w);
        as[q] = r.b;
      }
#pragma unroll
      for (int u = 0; u < 5; ++u) {
        bf16x8 bfr = *(const bf16x8*)(Bb + bB + ks * 10240 + u * 256);
#pragma unroll
        for (int q = 0; q < 4; ++q)
          acc[q][u] = __builtin_amdgcn_mfma_f32_16x16x32_bf16(
              as[q], bfr, acc[q][u], 0, 0, 0);
      }
    }
    __builtin_amdgcn_s_setprio(0);
    if (t < 35) {
#pragma unroll
      for (int k = 0; k < 8; ++k) afC[k] = afN[k];
#pragma unroll
      for (int k = 0; k < 4; ++k) gsC[k] = gsN[k];
    }
    __builtin_amdgcn_sched_barrier(0);
    // DMAs (older than the 12 reg loads) drained; ds_reads drained; the
    // 12 A/g reg loads for t+1 legally stay in flight across the barrier.
    asm volatile("s_waitcnt vmcnt(12) lgkmcnt(0)" ::: "memory");
    __builtin_amdgcn_s_barrier();
    __builtin_amdgcn_sched_barrier(0);
  }

  // ---- epilogue1: h1 = relu(hij + hi + hj + pb1) -> LDS bf16 [20][256][8] --
  {
    float hib[5];
#pragma unroll
    for (int u = 0; u < 5; ++u) {
      int h = wh * 80 + u * 16 + (lane & 15);
      hib[u] = hi[i * 160 + h] + pb1p[h];
    }
#pragma unroll
    for (int q = 0; q < 4; ++q) {
      int jl = wj * 64 + q * 16 + ((lane >> 4) << 2);
#pragma unroll
      for (int r = 0; r < 4; ++r) {
        const float* hjr = hj + (size_t)(jl + r) * 160;
#pragma unroll
        for (int u = 0; u < 5; ++u) {
          int h = wh * 80 + u * 16 + (lane & 15);
          float v = fmaxf(acc[q][u][r] + hib[u] + hjr[h], 0.f);
          *(u16*)(smem + ((h >> 3) * 256 + jl + r) * 16 + (h & 7) * 2) = f2bf(v);
        }
      }
    }
  }
  __syncthreads();

  // ---- GEMM2: h2 = h1' @ W2 (K=160), 3 chunks (8,8,4 kgrps) ----
  f32x4 acc2[4][5] = {};
  for (int c = 0; c < 3; ++c) {
    const int G64 = (c < 2) ? 20 : 10;
    for (int g0 = w; g0 < G64; g0 += 8) {
      const u16* src = W2kg + ((size_t)c * 1280 + g0 * 64 + lane) * 8;
      gload_lds16(src, smem + 81920 + g0 * 1024);
    }
    __syncthreads();
    const int nks = (c < 2) ? 2 : 1;
    for (int ks = 0; ks < nks; ++ks) {
      const int kl = ks * 4 + (lane >> 4);
      bf16x8 af2[4];
#pragma unroll
      for (int q = 0; q < 4; ++q)
        af2[q] = *(const bf16x8*)(smem + ((c * 8 + kl) * 256 + wj * 64 + q * 16 + (lane & 15)) * 16);
#pragma unroll
      for (int u = 0; u < 5; ++u) {
        bf16x8 b2 = *(const bf16x8*)(smem + 81920 + (kl * 160 + wh * 80 + u * 16 + (lane & 15)) * 16);
#pragma unroll
        for (int q = 0; q < 4; ++q)
          acc2[q][u] = __builtin_amdgcn_mfma_f32_16x16x32_bf16(af2[q], b2, acc2[q][u], 0, 0, 0);
      }
    }
    __syncthreads();
  }

  // ---- epilogue2: s = relu(h2 + pb2).w3 ; out = clip((mi+mj+s)/3) ----
  {
    float w3v[5], b2v[5];
#pragma unroll
    for (int u = 0; u < 5; ++u) {
      int h2 = wh * 80 + u * 16 + (lane & 15);
      w3v[u] = w3p[h2]; b2v[u] = pb2p[h2];
    }
#pragma unroll
    for (int q = 0; q < 4; ++q) {
#pragma unroll
      for (int r = 0; r < 4; ++r) {
        float sp = 0.f;
#pragma unroll
        for (int u = 0; u < 5; ++u)
          sp += fmaxf(acc2[q][u][r] + b2v[u], 0.f) * w3v[u];
        sp += __shfl_xor(sp, 1);
        sp += __shfl_xor(sp, 2);
        sp += __shfl_xor(sp, 4);
        sp += __shfl_xor(sp, 8);
        if ((lane & 15) == 0) {
          int jl = wj * 64 + q * 16 + ((lane >> 4) << 2) + r;
          *(float*)(smem + 102400 + (jl * 2 + wh) * 4) = sp;
        }
      }
    }
  }
  __syncthreads();
  if (tid < 256) {
    float s = *(const float*)(smem + 102400 + tid * 8) +
              *(const float*)(smem + 102400 + tid * 8 + 4) + pb3[0];
    float v = (mv[i] + mv[tid] + s) * (1.f / 3.f);
    out[i * 256 + tid] = fminf(fmaxf(v, 0.f), 1.f);
  }
}

// ---------------------------------------------------------------------------
extern "C" void kernel_launch(void* const* d_in, const int* in_sizes, int n_in,
                              void* d_out, int out_size, void* d_ws, size_t ws_size,
                              hipStream_t stream) {
  (void)in_sizes; (void)n_in; (void)out_size; (void)ws_size;
  const float* e    = (const float*)d_in[0];
  const int*   sst  = (const int*)d_in[1];
  const int*   swd  = (const int*)d_in[2];
  const float* aW1  = (const float*)d_in[3];
  const float* ab1  = (const float*)d_in[4];
  const float* aW2  = (const float*)d_in[5];
  const float* ab2  = (const float*)d_in[6];
  const float* aW3  = (const float*)d_in[7];
  const float* ab3  = (const float*)d_in[8];
  const float* mW1  = (const float*)d_in[9];
  const float* mb1  = (const float*)d_in[10];
  const float* mW2  = (const float*)d_in[11];
  const float* mb2  = (const float*)d_in[12];
  const float* mW3  = (const float*)d_in[13];
  const float* mb3  = (const float*)d_in[14];
  const float* pW1  = (const float*)d_in[15];
  const float* pb1  = (const float*)d_in[16];
  const float* pW2  = (const float*)d_in[17];
  const float* pb2  = (const float*)d_in[18];
  const float* pW3  = (const float*)d_in[19];
  const float* pb3  = (const float*)d_in[20];
  float* out = (float*)d_out;

  char* ws = (char*)d_ws;
  size_t off = 0;
  auto alloc = [&](size_t bytes) -> char* {
    char* p = ws + off;
    off += (bytes + 255) & ~(size_t)255;
    return p;
  };
  float* attn  = (float*)alloc(2048ULL*4);
  float* g     = (float*)alloc(256ULL*2304*4);
  float* hi    = (float*)alloc(256ULL*160*4);
  float* hj    = (float*)alloc(256ULL*160*4);
  float* mv    = (float*)alloc(256ULL*4);
  float* h1p   = (float*)alloc(4ULL*2048*160*4);
  float* pp    = (float*)alloc(6ULL*256*480*4);
  u16*   aW1Th = (u16*)alloc(160ULL*768*2);
  u16*   aW1Tl = (u16*)alloc(160ULL*768*2);
  u16*   Wcath = (u16*)alloc(480ULL*2304*2);
  u16*   Wcatl = (u16*)alloc(480ULL*2304*2);
  float* aW2p  = (float*)alloc(152ULL*160*4);
  float* mW2p  = (float*)alloc(152ULL*160*4);
  u16*   gkg   = (u16*)alloc(288ULL*256*8*2);
  u16*   Wckg  = (u16*)alloc(288ULL*160*8*2);
  u16*   W2kg  = (u16*)alloc(24ULL*1280*2);
  float* pb1p  = (float*)alloc(160ULL*4);
  float* pb2p  = (float*)alloc(160ULL*4);
  float* w3p   = (float*)alloc(160ULL*4);

  k_prepT<<<dim3(36, 6), 256, 0, stream>>>(mW1, pW1, aW1, aW2, mW2, pW2,
                                           pb1, pb2, pW3,
                                           Wcath, Wcatl, aW1Th, aW1Tl, Wckg,
                                           aW2p, mW2p, W2kg, pb1p, pb2p, w3p);
  k_attn1<<<dim3(64, 4), 256, 0, stream>>>(e, aW1Th, aW1Tl, h1p);
  k_attn2<<<256, 256, 0, stream>>>(h1p, aW2p, ab1, ab2, aW3, ab3, attn);
  k_spans<<<256, 256, 0, stream>>>(e, attn, sst, swd, g, gkg);
  k_span1<<<dim3(16, 3, 6), 128, 0, stream>>>(g, Wcath, Wcatl, pp);
  k_span2r<<<32, 256, 0, stream>>>(pp, mb1, mW2p, mb2, mW3, mb3, hi, hj, mv);
  k_hij9<<<256, 512, 0, stream>>>(g, gkg, Wckg, hi, hj, pb1p,
                                  W2kg, pb2p, w3p, pb3, mv, out);
}